// Round 13
// baseline (69.034 us; speedup 1.0000x reference)
//
#include <hip/hip_runtime.h>
#include <hip/hip_bf16.h>

#define B_ 8
#define C_ 96
#define H_ 64
#define W_ 96
#define DD 21
#define LDSTm 37           // Dst row stride (floats): 5 mod 32 -> conflict-light scatter
#define RAWS 49            // prep LDS row stride (uints): conflict-free gather
#define FRAG 512           // ushorts per fragment (64 lanes x 16B)

typedef __attribute__((ext_vector_type(8))) short sh8;
typedef __attribute__((ext_vector_type(4))) float fx4;

// Fragment-major bf16 tensors: innermost [lane(64)][e(8)] = 1KB per k-block.
// d1F: [b][y][p][ut(3)][k(3)][lane][8]
// d2F: [b][yp(104)][p][wt(5)][k(3)][lane][8]   (yp/x padded, borders zero)
__device__ __attribute__((aligned(16))) unsigned short g_d1F[B_*H_*2*3*3*FRAG];
__device__ __attribute__((aligned(16))) unsigned short g_d2F[(size_t)B_*104*2*5*3*FRAG];

// One fused prep kernel: grid (168, B).   [R10 version, verbatim]
__global__ __launch_bounds__(256) void prep_all(const float* __restrict__ d1,
                                                const float* __restrict__ d2) {
  __shared__ unsigned int raw[C_*RAWS];    // [c][w] packed (p0 | p1<<16)
  const int b = blockIdx.y;
  const int t = blockIdx.x;

  if (t >= 64) {
    const int yp = t - 64;
    unsigned short* ob = g_d2F + (size_t)(b*104 + yp)*(2*15*FRAG);
    if (yp < 20 || yp >= 84) {             // border row: pure zero-fill
      uint4 z; z.x = z.y = z.z = z.w = 0u;
      for (int s = threadIdx.x; s < 1920; s += 256)
        *((uint4*)ob + s) = z;
      return;
    }
    const int y = yp - 20;
    for (int idx = threadIdx.x; idx < C_*48; idx += 256) {
      int c = idx / 48, w = idx % 48;
      const float2 v = *(const float2*)(d2 + (((b*C_ + c)*H_ + y)*W_ + 2*w));
      __hip_bfloat16 h0 = __float2bfloat16(v.x), h1 = __float2bfloat16(v.y);
      raw[c*RAWS + w] = (unsigned)*(unsigned short*)&h0 |
                        ((unsigned)*(unsigned short*)&h1 << 16);
    }
    __syncthreads();
    for (int s = threadIdx.x; s < 2*15*64; s += 256) {
      int lane = s & 63, q = s >> 6;
      int kk = q % 3, wt = (q/3) % 5, p = q / 15;
      int w = wt*16 + (lane & 15) - 10;    // x-pad: stored col = w' - 10
      int cb = kk*32 + (lane >> 4)*8;
      uint4 o; o.x = o.y = o.z = o.w = 0u;
      if (w >= 0 && w < 48) {
        unsigned short tmp[8];
        #pragma unroll
        for (int e = 0; e < 8; ++e) {
          unsigned pk = raw[(cb + e)*RAWS + w];
          tmp[e] = (unsigned short)(p ? (pk >> 16) : pk);
        }
        o = *(const uint4*)tmp;
      }
      *(uint4*)(ob + (size_t)s*8) = o;
    }
  } else {
    const int y = t;
    for (int idx = threadIdx.x; idx < C_*48; idx += 256) {
      int c = idx / 48, w = idx % 48;
      const float2 v = *(const float2*)(d1 + (((b*C_ + c)*H_ + y)*W_ + 2*w));
      __hip_bfloat16 h0 = __float2bfloat16(v.x), h1 = __float2bfloat16(v.y);
      raw[c*RAWS + w] = (unsigned)*(unsigned short*)&h0 |
                        ((unsigned)*(unsigned short*)&h1 << 16);
    }
    __syncthreads();
    unsigned short* ob = g_d1F + (size_t)(b*H_ + y)*(2*9*FRAG);
    for (int s = threadIdx.x; s < 2*9*64; s += 256) {
      int lane = s & 63, q = s >> 6;
      int kk = q % 3, ut = (q/3) % 3, p = q / 9;
      int w = ut*16 + (lane & 15);
      int cb = kk*32 + (lane >> 4)*8;
      unsigned short tmp[8];
      #pragma unroll
      for (int e = 0; e < 8; ++e) {
        unsigned pk = raw[(cb + e)*RAWS + w];
        tmp[e] = (unsigned short)(p ? (pk >> 16) : pk);
      }
      *(uint4*)(ob + (size_t)s*8) = *(const uint4*)tmp;
    }
  }
}

// LDS-only barrier: lgkmcnt(0)+s_barrier WITHOUT vmcnt drain -- in-flight
// global_load_lds staging survives the barrier (T4 counted-vmcnt pattern).
#define SYNC_LDS asm volatile("s_waitcnt lgkmcnt(0)\n\ts_barrier" ::: "memory")

// Stage full B row (30 frags = 30KB, both parities) into LDS buffer BUF via
// global_load_lds: zero VGPR cost, wave-uniform LDS dest + lane*16B (m104).
// Wave wv stages frags f = wv*5..wv*5+4. d2F layout is linear in f.
#define STAGE(ROW, BUF) do {                                                   \
    const unsigned short* rb_ =                                                \
        g_d2F + (size_t)((b*104 + (ROW))*2)*(15*FRAG);                         \
    _Pragma("unroll")                                                          \
    for (int s_ = 0; s_ < 5; ++s_) {                                           \
      const int f_ = wv*5 + s_;                                                \
      __builtin_amdgcn_global_load_lds(                                        \
          (const unsigned int*)(rb_ + f_*FRAG + lane*8),                       \
          (unsigned int*)&Blds[((BUF)*30 + f_)*FRAG], 16, 0, 0);               \
    }                                                                          \
  } while (0)

// Wait for the PREVIOUS row's staging (own 5 loads) while leaving the just-
// issued next-row loads in flight; then block barrier.
#define WAIT_STAGE(N) do {                                                     \
    asm volatile("s_waitcnt vmcnt(" #N ")" ::: "memory");                      \
    SYNC_LDS;                                                                  \
  } while (0)

// Compute row I from LDS buffer BUF: 9 ds_read_b128 B-frags + 9 MFMA, band
// extract into per-mt Dst (shared by the p-wave pair), barrier2, coalesced
// NT store. barrier2 also certifies all waves' B-reads of BUF complete
// before the next iteration's STAGE overwrites the other buffer / this one.
#define COMPUTE(I, BUF) do {                                                   \
    const unsigned short* bb_ = &Blds[((BUF)*30 + p*15)*FRAG + lane*8];        \
    fx4 acc[3] = {fx4{0,0,0,0}, fx4{0,0,0,0}, fx4{0,0,0,0}};                   \
    _Pragma("unroll")                                                          \
    for (int k_ = 0; k_ < 3; ++k_)                                             \
      _Pragma("unroll")                                                        \
      for (int n_ = 0; n_ < 3; ++n_) {                                         \
        sh8 bf_ = *(const sh8*)(bb_ + ((mt + n_)*3 + k_)*FRAG);                \
        acc[n_] = __builtin_amdgcn_mfma_f32_16x16x32_bf16(aF[k_], bf_,         \
                                                          acc[n_], 0, 0, 0);   \
      }                                                                        \
    _Pragma("unroll")                                                          \
    for (int n_ = 0; n_ < 3; ++n_)                                             \
      _Pragma("unroll")                                                        \
      for (int r_ = 0; r_ < 4; ++r_) {                                         \
        int j_ = 16*n_ + lr - 4*lg - r_;                                       \
        if (j_ >= 0 && j_ < DD)                                                \
          Dst[mt][j_*LDSTm + 2*(4*lg + r_) + p] = acc[n_][r_];                 \
      }                                                                        \
    SYNC_LDS;                                                                  \
    size_t obase = (size_t)((b*441 + (I)*DD)*H_ + y)*W_ + 2*m0;                \
    for (int q_ = p*64 + lane; q_ < DD*32; q_ += 128) {                        \
      int j_ = q_ >> 5, xl_ = q_ & 31;                                         \
      __builtin_nontemporal_store(Dst[mt][j_*LDSTm + xl_]*scale,               \
                                  out + obase + (size_t)j_*(H_*W_) + xl_);     \
    }                                                                          \
  } while (0)

// One block per (b, y): 384 threads = 6 waves = (mt 0..2) x (p 0..1).
// Per i in [0,21): B row yp=y+2i staged ONCE to LDS, consumed by all 6 waves
// (L2 read 580->322 MB; fragment access = ds_read_b128 not L2 round-trip).
// Double-buffered rows: loads for row i+1 in flight during ALL of row i's
// compute (~1500cy slack). 512 blocks = exactly 2/CU (70.8KB LDS), 12
// waves/CU, fully resident.
// G=A.B^T band: out[b, i*21+j, y, 2u+p] = G_p[u, u+j], j in [0,21).
__global__ __launch_bounds__(384, 3) void corr_main(const float* __restrict__ s1,
                                                    const float* __restrict__ s2,
                                                    const float* __restrict__ os,
                                                    float* __restrict__ out) {
  __shared__ unsigned short Blds[2*30*FRAG];   // 61440 B: 2 x full B row
  __shared__ float Dst[3][DD*LDSTm];           // 9324 B: per-mt transpose buf
  const int gid = blockIdx.x;
  const int b = gid & 7;                   // XCD affinity
  const int y = gid >> 3;                  // [0,64)
  const int wv = threadIdx.x >> 6;
  const int p = wv & 1, mt = wv >> 1;
  const int m0 = mt << 4;
  const int lane = threadIdx.x & 63;
  const int lr = lane & 15, lg = lane >> 4;
  const float scale = s1[0]*s2[0] / (96.0f * os[0]);

  sh8 aF[3];
  {
    const unsigned short* aB =
        g_d1F + (size_t)((b*H_ + y)*2 + p)*(9*FRAG) + (size_t)mt*3*FRAG + lane*8;
    #pragma unroll
    for (int k = 0; k < 3; ++k)
      aF[k] = *(const sh8*)(aB + k*FRAG);
  }

  STAGE(y, 0);                             // prologue: row 0 -> buf0
  #pragma unroll 1
  for (int r = 0; r < 20; ++r) {
    STAGE(y + 2*(r + 1), (r + 1) & 1);     // next row in flight
    WAIT_STAGE(5);                         // own prev-row loads done; barrier
    COMPUTE(r, r & 1);                     // includes barrier2 (Dst handoff)
  }
  WAIT_STAGE(0);                           // last row: drain fully
  COMPUTE(20, 0);
}

extern "C" void kernel_launch(void* const* d_in, const int* in_sizes, int n_in,
                              void* d_out, int out_size, void* d_ws, size_t ws_size,
                              hipStream_t stream) {
  const float* d1 = (const float*)d_in[0];
  const float* d2 = (const float*)d_in[1];
  const float* s1 = (const float*)d_in[2];
  const float* s2 = (const float*)d_in[3];
  const float* os = (const float*)d_in[5];   // inter_scale (d_in[4]) unused

  prep_all<<<dim3(168, B_), 256, 0, stream>>>(d1, d2);
  corr_main<<<B_*H_, 384, 0, stream>>>(s1, s2, os, (float*)d_out);
}

// Round 14
// 44.747 us; speedup vs baseline: 1.5428x; 1.5428x over previous
//
#include <hip/hip_runtime.h>
#include <hip/hip_bf16.h>

#define B_ 8
#define C_ 96
#define H_ 64
#define W_ 96
#define DD 21
#define NI 3               // i-values per block
#define ISPLIT 7           // 21 / NI
#define LDSTm 37           // Dst row stride (floats): 5 mod 32 -> conflict-light scatter
#define RAWS 49            // prep LDS row stride (uints): conflict-free gather

typedef __attribute__((ext_vector_type(8))) short sh8;
typedef __attribute__((ext_vector_type(4))) float fx4;

// Fragment-major bf16 tensors: innermost [lane(64)][e(8)] = 1KB per k-block,
// so a wave's MFMA operand load is base + lane*16B (fully coalesced).
// d1F: [b][y][p][ut(3)][k(3)][lane][8]
// d2F: [b][yp(104)][p][wt(5)][k(3)][lane][8]   (yp/x padded, borders zero)
__device__ __attribute__((aligned(16))) unsigned short g_d1F[B_*H_*2*3*3*512];
__device__ __attribute__((aligned(16))) unsigned short g_d2F[(size_t)B_*104*2*5*3*512];

// Fused prep kernel, XCD-ALIGNED 1D grid: gid = b + 8*t, so batch b's
// producer blocks run on XCD b -- the same XCD whose corr blocks (b = gid&7)
// consume d2F[b] (3.2 MB, fits the 4 MB per-XCD L2). First-touch locality.
//  t in [0,64):    d1 row y=t          -> g_d1F
//  t in [64,168):  d2 padded row yp=t-64 (zero-fill if border) -> g_d2F
__global__ __launch_bounds__(256) void prep_all(const float* __restrict__ d1,
                                                const float* __restrict__ d2) {
  __shared__ unsigned int raw[C_*RAWS];    // [c][w] packed (p0 | p1<<16)
  const int b = blockIdx.x & 7;
  const int t = blockIdx.x >> 3;

  if (t >= 64) {
    const int yp = t - 64;
    unsigned short* ob = g_d2F + (size_t)(b*104 + yp)*(2*15*512);
    if (yp < 20 || yp >= 84) {             // border row: pure zero-fill
      uint4 z; z.x = z.y = z.z = z.w = 0u;
      for (int s = threadIdx.x; s < 1920; s += 256)
        *((uint4*)ob + s) = z;
      return;
    }
    const int y = yp - 20;
    for (int idx = threadIdx.x; idx < C_*48; idx += 256) {
      int c = idx / 48, w = idx % 48;
      const float2 v = *(const float2*)(d2 + (((b*C_ + c)*H_ + y)*W_ + 2*w));
      __hip_bfloat16 h0 = __float2bfloat16(v.x), h1 = __float2bfloat16(v.y);
      raw[c*RAWS + w] = (unsigned)*(unsigned short*)&h0 |
                        ((unsigned)*(unsigned short*)&h1 << 16);
    }
    __syncthreads();
    for (int s = threadIdx.x; s < 2*15*64; s += 256) {
      int lane = s & 63, q = s >> 6;
      int kk = q % 3, wt = (q/3) % 5, p = q / 15;
      int w = wt*16 + (lane & 15) - 10;    // x-pad: stored col = w' - 10
      int cb = kk*32 + (lane >> 4)*8;
      uint4 o; o.x = o.y = o.z = o.w = 0u;
      if (w >= 0 && w < 48) {
        unsigned short tmp[8];
        #pragma unroll
        for (int e = 0; e < 8; ++e) {
          unsigned pk = raw[(cb + e)*RAWS + w];
          tmp[e] = (unsigned short)(p ? (pk >> 16) : pk);
        }
        o = *(const uint4*)tmp;
      }
      *(uint4*)(ob + (size_t)s*8) = o;
    }
  } else {
    const int y = t;
    for (int idx = threadIdx.x; idx < C_*48; idx += 256) {
      int c = idx / 48, w = idx % 48;
      const float2 v = *(const float2*)(d1 + (((b*C_ + c)*H_ + y)*W_ + 2*w));
      __hip_bfloat16 h0 = __float2bfloat16(v.x), h1 = __float2bfloat16(v.y);
      raw[c*RAWS + w] = (unsigned)*(unsigned short*)&h0 |
                        ((unsigned)*(unsigned short*)&h1 << 16);
    }
    __syncthreads();
    unsigned short* ob = g_d1F + (size_t)(b*H_ + y)*(2*9*512);
    for (int s = threadIdx.x; s < 2*9*64; s += 256) {
      int lane = s & 63, q = s >> 6;
      int kk = q % 3, ut = (q/3) % 3, p = q / 9;
      int w = ut*16 + (lane & 15);
      int cb = kk*32 + (lane >> 4)*8;
      unsigned short tmp[8];
      #pragma unroll
      for (int e = 0; e < 8; ++e) {
        unsigned pk = raw[(cb + e)*RAWS + w];
        tmp[e] = (unsigned short)(p ? (pk >> 16) : pk);
      }
      *(uint4*)(ob + (size_t)s*8) = *(const uint4*)tmp;
    }
  }
}

// LDS-only barrier: orders extract(ds_write) -> store(ds_read) across the
// block WITHOUT draining vmcnt -- prefetched global loads stay in flight
// across the barrier (the compiler auto-waits the right vmcnt before the
// MFMAs that consume them). "memory" clobber pins LDS ops on both sides.
#define SYNC_LDS asm volatile("s_waitcnt lgkmcnt(0)\n\ts_barrier" ::: "memory")

// Token-pasting macros over NAMED register arrays (bF0/bF1): every array
// index is compile-time after unroll -> no scratch (rule #20; R5 lesson).
#define LOADB(BF, ROW) do {                                                    \
    const unsigned short* rb_ =                                                \
        g_d2F + (size_t)(((b*104 + (ROW))*2 + p)*5 + mt)*(3*512) + lane*8;     \
    _Pragma("unroll")                                                          \
    for (int n_ = 0; n_ < 3; ++n_)                                             \
      _Pragma("unroll")                                                        \
      for (int k_ = 0; k_ < 3; ++k_)                                           \
        BF[k_*3+n_] = *(const sh8*)(rb_ + (n_*3 + k_)*512);                    \
  } while (0)

// Output stores NON-TEMPORAL (R10: -2.3us): d_out is write-once/never-read;
// bypassing L2 allocation keeps d2F resident per-XCD.
#define COMBO(BF, I, BUF) do {                                                 \
    fx4 acc[3] = {fx4{0,0,0,0}, fx4{0,0,0,0}, fx4{0,0,0,0}};                   \
    _Pragma("unroll")                                                          \
    for (int k_ = 0; k_ < 3; ++k_)                                             \
      _Pragma("unroll")                                                        \
      for (int n_ = 0; n_ < 3; ++n_)                                           \
        acc[n_] = __builtin_amdgcn_mfma_f32_16x16x32_bf16(aF[k_], BF[k_*3+n_], \
                                                          acc[n_], 0, 0, 0);   \
    _Pragma("unroll")                                                          \
    for (int n_ = 0; n_ < 3; ++n_)                                             \
      _Pragma("unroll")                                                        \
      for (int r_ = 0; r_ < 4; ++r_) {                                         \
        int j_ = 16*n_ + lr - 4*lg - r_;                                       \
        if (j_ >= 0 && j_ < DD)                                                \
          Dst[BUF][j_*LDSTm + 2*(4*lg + r_) + p] = acc[n_][r_];                \
      }                                                                        \
    SYNC_LDS;                                                                  \
    size_t obase = (size_t)((b*441 + (I)*DD)*H_ + y)*W_ + 2*m0;                \
    for (int s_ = threadIdx.x; s_ < DD*32; s_ += 128) {                        \
      int j_ = s_ >> 5, xl_ = s_ & 31;                                         \
      __builtin_nontemporal_store(Dst[BUF][j_*LDSTm + xl_]*scale,              \
                                  out + obase + (size_t)j_*(H_*W_) + xl_);     \
    }                                                                          \
  } while (0)
// Dst ping-pong race check: extract into BUF happens only after the barrier
// that followed the previous store of the SAME buffer (two combos earlier)
// -- race-free with one LDS barrier per combo.

// One block per (b, m-tile, y, i-segment): 128 threads = 2 waves (p=0,1).
// Wave (p): A[u][c]=d1[b,c,y,2u+p], u in [m0,m0+16); B[w'][c]=d2pad[...,2w'+p].
// G=A·B^T band: out[b, i*21+j, y, 2u+p] = G[u, u+j], j in [0,21).
// B rows register-double-buffered: LOADB(next) issues before COMBO(cur), and
// SYNC_LDS lets those loads stay outstanding across the barrier.
__global__ __launch_bounds__(128, 4) void corr_main(const float* __restrict__ s1,
                                                    const float* __restrict__ s2,
                                                    const float* __restrict__ os,
                                                    float* __restrict__ out) {
  __shared__ float Dst[2][DD*LDSTm];
  const int gid = blockIdx.x;
  const int b = gid & 7;                   // XCD affinity (matches prep)
  int t = gid >> 3;
  const int mt = t % 3; t /= 3;
  const int m0 = mt << 4;
  const int y = t & 63;
  const int i0 = (t >> 6) * NI;
  const int p = threadIdx.x >> 6;
  const int lane = threadIdx.x & 63;
  const int lr = lane & 15, lg = lane >> 4;
  const float scale = s1[0]*s2[0] / (96.0f * os[0]);

  sh8 aF[3];
  {
    const unsigned short* aB =
        g_d1F + (size_t)((b*H_ + y)*2 + p)*(9*512) + (size_t)mt*3*512 + lane*8;
    #pragma unroll
    for (int k = 0; k < 3; ++k)
      aF[k] = *(const sh8*)(aB + k*512);
  }

  sh8 bF0[9], bF1[9];
  const int yb = y + 2*i0;                 // B row for i0 (rows step by 2)
  LOADB(bF0, yb);
  LOADB(bF1, yb + 2);
  COMBO(bF0, i0,     0);
  LOADB(bF0, yb + 4);
  COMBO(bF1, i0 + 1, 1);
  COMBO(bF0, i0 + 2, 0);
}

extern "C" void kernel_launch(void* const* d_in, const int* in_sizes, int n_in,
                              void* d_out, int out_size, void* d_ws, size_t ws_size,
                              hipStream_t stream) {
  const float* d1 = (const float*)d_in[0];
  const float* d2 = (const float*)d_in[1];
  const float* s1 = (const float*)d_in[2];
  const float* s2 = (const float*)d_in[3];
  const float* os = (const float*)d_in[5];   // inter_scale (d_in[4]) unused

  prep_all<<<168*B_, 256, 0, stream>>>(d1, d2);
  corr_main<<<B_*3*H_*ISPLIT, 128, 0, stream>>>(s1, s2, os, (float*)d_out);
}

// Round 15
// 44.552 us; speedup vs baseline: 1.5495x; 1.0044x over previous
//
#include <hip/hip_runtime.h>
#include <hip/hip_bf16.h>

#define B_ 8
#define C_ 96
#define H_ 64
#define W_ 96
#define DD 21
#define NI 3               // i-values per block
#define ISPLIT 7           // 21 / NI
#define LDSTm 37           // Dst row stride (floats): 5 mod 32 -> conflict-light scatter
#define RAWS 49            // prep LDS row stride (uints): conflict-free gather

typedef __attribute__((ext_vector_type(8))) short sh8;
typedef __attribute__((ext_vector_type(4))) float fx4;

// Fragment-major bf16 tensors: innermost [lane(64)][e(8)] = 1KB per k-block,
// so a wave's MFMA operand load is base + lane*16B (fully coalesced).
// d1F: [b][y][p][ut(3)][k(3)][lane][8]
// d2F: [b][yp(104)][p][wt(5)][k(3)][lane][8]   (yp/x padded, borders zero)
__device__ __attribute__((aligned(16))) unsigned short g_d1F[B_*H_*2*3*3*512];
__device__ __attribute__((aligned(16))) unsigned short g_d2F[(size_t)B_*104*2*5*3*512];

// Fused prep kernel, XCD-ALIGNED 1D grid: gid = b + 8*t, so batch b's
// producer blocks run on XCD b -- the same XCD whose corr blocks (b = gid&7)
// consume d2F[b] (3.2 MB, fits the 4 MB per-XCD L2). First-touch locality.
// (R14: -4.1us)
//  t in [0,64):    d1 row y=t          -> g_d1F
//  t in [64,168):  d2 padded row yp=t-64 (zero-fill if border) -> g_d2F
__global__ __launch_bounds__(256) void prep_all(const float* __restrict__ d1,
                                                const float* __restrict__ d2) {
  __shared__ unsigned int raw[C_*RAWS];    // [c][w] packed (p0 | p1<<16)
  const int b = blockIdx.x & 7;
  const int t = blockIdx.x >> 3;

  if (t >= 64) {
    const int yp = t - 64;
    unsigned short* ob = g_d2F + (size_t)(b*104 + yp)*(2*15*512);
    if (yp < 20 || yp >= 84) {             // border row: pure zero-fill
      uint4 z; z.x = z.y = z.z = z.w = 0u;
      for (int s = threadIdx.x; s < 1920; s += 256)
        *((uint4*)ob + s) = z;
      return;
    }
    const int y = yp - 20;
    for (int idx = threadIdx.x; idx < C_*48; idx += 256) {
      int c = idx / 48, w = idx % 48;
      const float2 v = *(const float2*)(d2 + (((b*C_ + c)*H_ + y)*W_ + 2*w));
      __hip_bfloat16 h0 = __float2bfloat16(v.x), h1 = __float2bfloat16(v.y);
      raw[c*RAWS + w] = (unsigned)*(unsigned short*)&h0 |
                        ((unsigned)*(unsigned short*)&h1 << 16);
    }
    __syncthreads();
    for (int s = threadIdx.x; s < 2*15*64; s += 256) {
      int lane = s & 63, q = s >> 6;
      int kk = q % 3, wt = (q/3) % 5, p = q / 15;
      int w = wt*16 + (lane & 15) - 10;    // x-pad: stored col = w' - 10
      int cb = kk*32 + (lane >> 4)*8;
      uint4 o; o.x = o.y = o.z = o.w = 0u;
      if (w >= 0 && w < 48) {
        unsigned short tmp[8];
        #pragma unroll
        for (int e = 0; e < 8; ++e) {
          unsigned pk = raw[(cb + e)*RAWS + w];
          tmp[e] = (unsigned short)(p ? (pk >> 16) : pk);
        }
        o = *(const uint4*)tmp;
      }
      *(uint4*)(ob + (size_t)s*8) = o;
    }
  } else {
    const int y = t;
    for (int idx = threadIdx.x; idx < C_*48; idx += 256) {
      int c = idx / 48, w = idx % 48;
      const float2 v = *(const float2*)(d1 + (((b*C_ + c)*H_ + y)*W_ + 2*w));
      __hip_bfloat16 h0 = __float2bfloat16(v.x), h1 = __float2bfloat16(v.y);
      raw[c*RAWS + w] = (unsigned)*(unsigned short*)&h0 |
                        ((unsigned)*(unsigned short*)&h1 << 16);
    }
    __syncthreads();
    unsigned short* ob = g_d1F + (size_t)(b*H_ + y)*(2*9*512);
    for (int s = threadIdx.x; s < 2*9*64; s += 256) {
      int lane = s & 63, q = s >> 6;
      int kk = q % 3, ut = (q/3) % 3, p = q / 9;
      int w = ut*16 + (lane & 15);
      int cb = kk*32 + (lane >> 4)*8;
      unsigned short tmp[8];
      #pragma unroll
      for (int e = 0; e < 8; ++e) {
        unsigned pk = raw[(cb + e)*RAWS + w];
        tmp[e] = (unsigned short)(p ? (pk >> 16) : pk);
      }
      *(uint4*)(ob + (size_t)s*8) = *(const uint4*)tmp;
    }
  }
}

// LDS-only barrier: orders extract(ds_write) -> store(ds_read) across the
// block WITHOUT draining vmcnt -- prefetched global loads stay in flight
// across the barrier (the compiler auto-waits the right vmcnt before the
// MFMAs that consume them). "memory" clobber pins LDS ops on both sides.
#define SYNC_LDS asm volatile("s_waitcnt lgkmcnt(0)\n\ts_barrier" ::: "memory")

// Token-pasting macros over NAMED register arrays (bF0/bF1): every array
// index is compile-time after unroll -> no scratch (rule #20; R5 lesson).
#define LOADB(BF, ROW) do {                                                    \
    const unsigned short* rb_ =                                                \
        g_d2F + (size_t)(((b*104 + (ROW))*2 + p)*5 + mt)*(3*512) + lane*8;     \
    _Pragma("unroll")                                                          \
    for (int n_ = 0; n_ < 3; ++n_)                                             \
      _Pragma("unroll")                                                        \
      for (int k_ = 0; k_ < 3; ++k_)                                           \
        BF[k_*3+n_] = *(const sh8*)(rb_ + (n_*3 + k_)*512);                    \
  } while (0)

// Output stores NON-TEMPORAL (R10: -2.3us) and now PACKED fx4 (this round's
// A/B): 4 scalar LDS reads (stride-37 rows -> ~2-way, free) assemble one
// 16B register vector, ONE nt store per thread-slot -> 4x fewer store
// instructions, 1KB per wave store instruction.
#define COMBO(BF, I, BUF) do {                                                 \
    fx4 acc[3] = {fx4{0,0,0,0}, fx4{0,0,0,0}, fx4{0,0,0,0}};                   \
    _Pragma("unroll")                                                          \
    for (int k_ = 0; k_ < 3; ++k_)                                             \
      _Pragma("unroll")                                                        \
      for (int n_ = 0; n_ < 3; ++n_)                                           \
        acc[n_] = __builtin_amdgcn_mfma_f32_16x16x32_bf16(aF[k_], BF[k_*3+n_], \
                                                          acc[n_], 0, 0, 0);   \
    _Pragma("unroll")                                                          \
    for (int n_ = 0; n_ < 3; ++n_)                                             \
      _Pragma("unroll")                                                        \
      for (int r_ = 0; r_ < 4; ++r_) {                                         \
        int j_ = 16*n_ + lr - 4*lg - r_;                                       \
        if (j_ >= 0 && j_ < DD)                                                \
          Dst[BUF][j_*LDSTm + 2*(4*lg + r_) + p] = acc[n_][r_];                \
      }                                                                        \
    SYNC_LDS;                                                                  \
    size_t obase = (size_t)((b*441 + (I)*DD)*H_ + y)*W_ + 2*m0;                \
    for (int q_ = threadIdx.x; q_ < DD*8; q_ += 128) {                         \
      int j_ = q_ >> 3, xi_ = q_ & 7;                                          \
      const float* rp_ = &Dst[BUF][j_*LDSTm + xi_*4];                          \
      fx4 v_; v_[0] = rp_[0]; v_[1] = rp_[1]; v_[2] = rp_[2]; v_[3] = rp_[3];  \
      v_ = v_ * scale;                                                         \
      __builtin_nontemporal_store(                                             \
          v_, (fx4*)(out + obase + (size_t)j_*(H_*W_) + xi_*4));               \
    }                                                                          \
  } while (0)
// Dst ping-pong race check: extract into BUF happens only after the barrier
// that followed the previous store of the SAME buffer (two combos earlier)
// -- race-free with one LDS barrier per combo.

// One block per (b, m-tile, y, i-segment): 128 threads = 2 waves (p=0,1).
// Wave (p): A[u][c]=d1[b,c,y,2u+p], u in [m0,m0+16); B[w'][c]=d2pad[...,2w'+p].
// G=A·B^T band: out[b, i*21+j, y, 2u+p] = G[u, u+j], j in [0,21).
// B rows register-double-buffered: LOADB(next) issues before COMBO(cur), and
// SYNC_LDS lets those loads stay outstanding across the barrier.
__global__ __launch_bounds__(128, 4) void corr_main(const float* __restrict__ s1,
                                                    const float* __restrict__ s2,
                                                    const float* __restrict__ os,
                                                    float* __restrict__ out) {
  __shared__ float Dst[2][DD*LDSTm];
  const int gid = blockIdx.x;
  const int b = gid & 7;                   // XCD affinity (matches prep)
  int t = gid >> 3;
  const int mt = t % 3; t /= 3;
  const int m0 = mt << 4;
  const int y = t & 63;
  const int i0 = (t >> 6) * NI;
  const int p = threadIdx.x >> 6;
  const int lane = threadIdx.x & 63;
  const int lr = lane & 15, lg = lane >> 4;
  const float scale = s1[0]*s2[0] / (96.0f * os[0]);

  sh8 aF[3];
  {
    const unsigned short* aB =
        g_d1F + (size_t)((b*H_ + y)*2 + p)*(9*512) + (size_t)mt*3*512 + lane*8;
    #pragma unroll
    for (int k = 0; k < 3; ++k)
      aF[k] = *(const sh8*)(aB + k*512);
  }

  sh8 bF0[9], bF1[9];
  const int yb = y + 2*i0;                 // B row for i0 (rows step by 2)
  LOADB(bF0, yb);
  LOADB(bF1, yb + 2);
  COMBO(bF0, i0,     0);
  LOADB(bF0, yb + 4);
  COMBO(bF1, i0 + 1, 1);
  COMBO(bF0, i0 + 2, 0);
}

extern "C" void kernel_launch(void* const* d_in, const int* in_sizes, int n_in,
                              void* d_out, int out_size, void* d_ws, size_t ws_size,
                              hipStream_t stream) {
  const float* d1 = (const float*)d_in[0];
  const float* d2 = (const float*)d_in[1];
  const float* s1 = (const float*)d_in[2];
  const float* s2 = (const float*)d_in[3];
  const float* os = (const float*)d_in[5];   // inter_scale (d_in[4]) unused

  prep_all<<<168*B_, 256, 0, stream>>>(d1, d2);
  corr_main<<<B_*3*H_*ISPLIT, 128, 0, stream>>>(s1, s2, os, (float*)d_out);
}